// Round 1
// baseline (729.618 us; speedup 1.0000x reference)
//
#include <hip/hip_runtime.h>

#define NB   256   // batch
#define NT   512   // time steps
#define NF   33    // features incl. flag channel
#define BOND 64
#define NOUT 32

typedef _Float16 h2 __attribute__((ext_vector_type(2)));

struct __align__(16) VP4 { h2 a, b, c, d; };

#if defined(__has_builtin)
#if __has_builtin(__builtin_amdgcn_fdot2)
#define HAVE_FDOT2 1
#endif
#endif

__device__ __forceinline__ h2 mk_h2(float a, float b) {
    h2 r;
    r.x = (_Float16)a;
    r.y = (_Float16)b;
    return r;
}

__device__ __forceinline__ float fdot2(h2 p, h2 q, float c) {
#ifdef HAVE_FDOT2
    return __builtin_amdgcn_fdot2(p, q, c, false);
#else
    return c + (float)p.x * (float)q.x + (float)p.y * (float)q.y;
#endif
}

// One workgroup per batch. 8 waves (512 thr). wave w owns bond-rows i in [8w, 8w+8),
// lane-id = output bond index j. Feature-core slice lives in VGPRs as packed f16
// pairs (pair along i). v carried in fp32 (wave 0); identity channel applied in fp32.
__global__ __launch_bounds__(512, 2)
void umps_chain(const float* __restrict__ x,
                const float* __restrict__ core,
                const float* __restrict__ alpha,
                const float* __restrict__ oc,
                float* __restrict__ out)
{
    const int tid = (int)threadIdx.x;
    const int j   = tid & 63;
    const int w   = tid >> 6;          // 0..7
    const int b   = (int)blockIdx.x;

    __shared__ __align__(16) h2 vpair[32];      // v packed as 32 f16 pairs
    __shared__ float part[8 * 64];              // per-wave partials

    // creg[ff][p] = ( C[8w+2p, ff+1, j], C[8w+2p+1, ff+1, j] ) as f16 pair
    h2 creg[32][4];
    {
        const float* cb = core + (size_t)(8 * w) * (NF * BOND) + BOND + j; // i=8w, f=1
        #pragma unroll
        for (int p = 0; p < 4; ++p) {
            const float* c0 = cb + (size_t)(2 * p) * (NF * BOND);
            const float* c1 = cb + (size_t)(2 * p + 1) * (NF * BOND);
            #pragma unroll
            for (int ff = 0; ff < 32; ++ff) {
                creg[ff][p] = mk_h2(c0[ff * BOND], c1[ff * BOND]);
            }
        }
    }

    float vreg = alpha[j];                 // authoritative copy lives in wave 0
    if (tid < 32) {
        vpair[tid] = mk_h2(alpha[2 * tid], alpha[2 * tid + 1]);
    }
    __syncthreads();

    const float* xb = x + (size_t)b * (NT * NF);

    #pragma unroll 1
    for (int t = 0; t < NT; ++t) {
        const float* xt = xb + t * NF;     // wave-uniform -> scalar loads

        // this wave's 4 v-pairs (broadcast 16B LDS read)
        VP4 vp = *(const VP4*)(&vpair[w * 4]);

        // partial[j] = sum_{f=1..32} x_f * sum_{i in slice} v_i * C[i,f,j]
        float acc = 0.f;
        #pragma unroll
        for (int ff = 0; ff < 32; ++ff) {
            float tmp = fdot2(vp.a, creg[ff][0], 0.f);
            tmp = fdot2(vp.b, creg[ff][1], tmp);
            tmp = fdot2(vp.c, creg[ff][2], tmp);
            tmp = fdot2(vp.d, creg[ff][3], tmp);
            acc = fmaf(xt[ff + 1], tmp, acc);
        }
        part[(w << 6) + j] = acc;
        __syncthreads();

        if (w == 0) {
            float s = 0.f;
            #pragma unroll
            for (int ww = 0; ww < 8; ++ww) s += part[(ww << 6) + j];
            // identity (flag) channel in exact fp32: x0 == 1
            float vnew = fmaf(xt[0], vreg, s);
            vreg = vnew;
            // repack v into f16 pairs for next step
            float e0 = __shfl(vnew, (j & 31) * 2, 64);
            float e1 = __shfl(vnew, (j & 31) * 2 + 1, 64);
            if (j < 32) vpair[j] = mk_h2(e0, e1);
        }
        __syncthreads();
    }

    // epilogue: out[b,:] = v @ output_core  (64 x 32)
    if (w == 0) part[j] = vreg;
    __syncthreads();
    if (tid < NOUT) {
        float s = 0.f;
        #pragma unroll
        for (int jj = 0; jj < BOND; ++jj)
            s = fmaf(part[jj], oc[jj * NOUT + tid], s);
        out[b * NOUT + tid] = s;
    }
}

extern "C" void kernel_launch(void* const* d_in, const int* in_sizes, int n_in,
                              void* d_out, int out_size, void* d_ws, size_t ws_size,
                              hipStream_t stream) {
    const float* x     = (const float*)d_in[0];  // (256, 512, 33) f32
    const float* core  = (const float*)d_in[1];  // (64, 33, 64) f32
    const float* alpha = (const float*)d_in[2];  // (64,) f32
    const float* oc    = (const float*)d_in[3];  // (64, 32) f32
    float* out = (float*)d_out;                  // (256, 32) f32

    umps_chain<<<dim3(NB), dim3(512), 0, stream>>>(x, core, alpha, oc, out);
}

// Round 2
// 569.467 us; speedup vs baseline: 1.2812x; 1.2812x over previous
//
#include <hip/hip_runtime.h>

#define NB   256   // batch
#define NT   512   // time steps
#define NF   33    // features incl. flag channel
#define NFP  36    // padded x row (16B-aligned rows in LDS)
#define BOND 64
#define NOUT 32

typedef _Float16 h2 __attribute__((ext_vector_type(2)));
typedef float    f4 __attribute__((ext_vector_type(4)));

__device__ __forceinline__ float fdot2(h2 p, h2 q, float c) {
    return __builtin_amdgcn_fdot2(p, q, c, false);   // v_dot2_f32_f16
}

__device__ __forceinline__ h2 pk2(float a, float b) {
    // v_cvt_pkrtz_f16_f32 : one instruction packs two f32 -> f16 pair
    auto r = __builtin_amdgcn_cvt_pkrtz(a, b);
    return __builtin_bit_cast(h2, r);
}

__device__ __forceinline__ h2 mk_h2(float a, float b) {
    h2 r;
    r.x = (_Float16)a;
    r.y = (_Float16)b;
    return r;
}

struct XRow {
    f4    q[8];    // f = 0..31
    float x32;     // f = 32
};

__device__ __forceinline__ void load_x(const float* __restrict__ xr, XRow& xv) {
    #pragma unroll
    for (int k = 0; k < 8; ++k) xv.q[k] = *(const f4*)(xr + 4 * k);
    xv.x32 = xr[32];
}

// One step of the chain. Loads x for step t+1 BEFORE the barrier so the LDS
// latency is absorbed by the barrier's lgkmcnt(0) drain.
__device__ __forceinline__ void step(const XRow& xv, XRow& xvn, int tnext,
                                     const h2 (&creg)[32][4], h2 (&vp)[4],
                                     float& v, float* __restrict__ partbuf,
                                     const float* __restrict__ xlds,
                                     int w, int j)
{
    // partial[j] = sum_{f=1..32} x_f * sum_{i in wave slice} v_i * C[i,f,j]
    float acc = 0.f;
    #pragma unroll
    for (int ff = 0; ff < 32; ++ff) {
        float tmp = fdot2(vp[0], creg[ff][0], 0.f);
        tmp = fdot2(vp[1], creg[ff][1], tmp);
        tmp = fdot2(vp[2], creg[ff][2], tmp);
        tmp = fdot2(vp[3], creg[ff][3], tmp);
        float xf = (ff < 31) ? xv.q[(ff + 1) >> 2][(ff + 1) & 3] : xv.x32;
        acc = fmaf(xf, tmp, acc);
    }
    partbuf[(w << 6) + j] = acc;

    load_x(xlds + tnext * NFP, xvn);     // prefetch next step's x (LDS)

    __syncthreads();

    // every wave redundantly reduces the 8 partials for its lane's j
    float p0 = partbuf[(0 << 6) + j], p1 = partbuf[(1 << 6) + j];
    float p2 = partbuf[(2 << 6) + j], p3 = partbuf[(3 << 6) + j];
    float p4 = partbuf[(4 << 6) + j], p5 = partbuf[(5 << 6) + j];
    float p6 = partbuf[(6 << 6) + j], p7 = partbuf[(7 << 6) + j];
    float s = ((p0 + p1) + (p2 + p3)) + ((p4 + p5) + (p6 + p7));
    v = fmaf(xv.q[0][0], v, s);          // identity (flag) channel, exact fp32

    // in-wave repack of this wave's 4 v-pairs (no LDS, no 2nd barrier)
    #pragma unroll
    for (int k = 0; k < 4; ++k) {
        float e0 = __shfl(v, 8 * w + 2 * k, 64);
        float e1 = __shfl(v, 8 * w + 2 * k + 1, 64);
        vp[k] = pk2(e0, e1);
    }
}

__global__ __launch_bounds__(512, 2)
void umps_chain(const float* __restrict__ x,
                const float* __restrict__ core,
                const float* __restrict__ alpha,
                const float* __restrict__ oc,
                float* __restrict__ out)
{
    const int tid = (int)threadIdx.x;
    const int j   = tid & 63;
    const int w   = tid >> 6;          // 0..7
    const int b   = (int)blockIdx.x;

    __shared__ __align__(16) float xlds[(NT + 1) * NFP];  // +1 row: prefetch overrun pad
    __shared__ float part[2][8 * 64];

    // ---- stage this batch's x into LDS (one-time, coalesced) ----
    const float* xb = x + (size_t)b * (NT * NF);
    for (int idx = tid; idx < NT * NF; idx += 512) {
        int t = idx / NF;
        int f = idx - t * NF;
        xlds[t * NFP + f] = xb[idx];
    }

    // ---- core slice into VGPRs as packed f16 pairs (pair along i) ----
    // creg[ff][p] = ( C[8w+2p, ff+1, j], C[8w+2p+1, ff+1, j] )
    h2 creg[32][4];
    {
        const float* cb = core + (size_t)(8 * w) * (NF * BOND) + BOND + j;
        #pragma unroll
        for (int p = 0; p < 4; ++p) {
            const float* c0 = cb + (size_t)(2 * p) * (NF * BOND);
            const float* c1 = cb + (size_t)(2 * p + 1) * (NF * BOND);
            #pragma unroll
            for (int ff = 0; ff < 32; ++ff) {
                creg[ff][p] = mk_h2(c0[ff * BOND], c1[ff * BOND]);
            }
        }
    }

    // ---- init carry: lane j holds v[j] (fp32, all waves identical) ----
    float v = alpha[j];
    h2 vp[4];
    #pragma unroll
    for (int k = 0; k < 4; ++k) {
        float e0 = __shfl(v, 8 * w + 2 * k, 64);
        float e1 = __shfl(v, 8 * w + 2 * k + 1, 64);
        vp[k] = pk2(e0, e1);
    }

    __syncthreads();   // xlds ready

    XRow xvA, xvB;
    load_x(xlds, xvA);

    #pragma unroll 1
    for (int t = 0; t < NT; t += 2) {
        step(xvA, xvB, t + 1, creg, vp, v, part[0], xlds, w, j);
        step(xvB, xvA, t + 2, creg, vp, v, part[1], xlds, w, j);
    }

    // ---- epilogue: out[b,:] = v @ output_core (64 x 32) ----
    if (w == 0) part[0][j] = v;
    __syncthreads();
    if (tid < NOUT) {
        float s = 0.f;
        #pragma unroll
        for (int jj = 0; jj < BOND; ++jj)
            s = fmaf(part[0][jj], oc[jj * NOUT + tid], s);
        out[b * NOUT + tid] = s;
    }
}

extern "C" void kernel_launch(void* const* d_in, const int* in_sizes, int n_in,
                              void* d_out, int out_size, void* d_ws, size_t ws_size,
                              hipStream_t stream) {
    const float* x     = (const float*)d_in[0];  // (256, 512, 33) f32
    const float* core  = (const float*)d_in[1];  // (64, 33, 64) f32
    const float* alpha = (const float*)d_in[2];  // (64,) f32
    const float* oc    = (const float*)d_in[3];  // (64, 32) f32
    float* out = (float*)d_out;                  // (256, 32) f32

    umps_chain<<<dim3(NB), dim3(512), 0, stream>>>(x, core, alpha, oc, out);
}